// Round 10
// baseline (502.455 us; speedup 1.0000x reference)
//
#include <hip/hip_runtime.h>
#include <hip/hip_bf16.h>

#define N1 (1u << 20)   // B*NH*HW = 16*64*1024

typedef __attribute__((ext_vector_type(8))) short s8v;
typedef __attribute__((ext_vector_type(4))) float f4v;

static __device__ __forceinline__ float sigm(float x){ return 1.f/(1.f + __expf(-x)); }
static __device__ __forceinline__ float tanh_(float x){ return 1.f - 2.f/(__expf(2.f*x) + 1.f); }

static __device__ __forceinline__ ushort f2b(float f){
  union { float f; uint u; } x; x.f = f;
  uint r = x.u + 0x7FFFu + ((x.u >> 16) & 1u);
  return (ushort)(r >> 16);
}

static __device__ __forceinline__ void red_atomic2(float s, float q, float* d, int b, int t){
  #pragma unroll
  for (int m = 32; m; m >>= 1){ s += __shfl_xor(s, m); q += __shfl_xor(q, m); }
  if ((t & 63) == 0){ atomicAdd(&d[b*2], s); atomicAdd(&d[b*2+1], q); }
}

// ---------------------------------------------------------------------------
// Mega-prep 1 (inputs only): xhm weight pack [tap][Co][Ci] + stats zero +
// x/h/m fp32->bf16 transpose [b][1024px][64].
// Blocks 0..5599: weight pack.  Blocks 5600..6367: 48 plane-transposes x16.
// ---------------------------------------------------------------------------
__global__ __launch_bounds__(256) void k_pre(
    const float* __restrict__ wX, ushort* __restrict__ dX,
    const float* __restrict__ wH, ushort* __restrict__ dH,
    const float* __restrict__ wM, ushort* __restrict__ dM,
    const float* __restrict__ x_t, ushort* __restrict__ xT,
    const float* __restrict__ h_t, ushort* __restrict__ hT,
    const float* __restrict__ m_t, ushort* __restrict__ mT,
    float* __restrict__ zs)
{
  const int bid = blockIdx.x, t = threadIdx.x;
  __shared__ __align__(16) float T[64][68];
  if (bid < 5600){
    if (bid == 0) zs[t] = 0.f;
    int idx = bid*256 + t;
    const float* s; ushort* d; int Co;
    if (idx < 716800){ s=wX; d=dX; Co=448; }
    else if ((idx -= 716800) < 409600){ s=wH; d=dH; Co=256; }
    else if ((idx -= 409600) < 307200){ s=wM; d=dM; Co=192; }
    else return;
    int ci = idx & 63; int r = idx >> 6; int co = r % Co; int tap = r / Co;
    d[idx] = f2b(s[((size_t)(co*64 + ci))*25 + tap]);
    return;
  }
  const int j = bid - 5600;
  const int p0 = (j & 15) << 6;
  const int lp = j >> 4;                 // 0..47
  const float* src; ushort* outT; int pl;
  if (lp < 16){ src = x_t; outT = xT; pl = lp; }
  else if (lp < 32){ src = h_t; outT = hT; pl = lp - 16; }
  else { src = m_t; outT = mT; pl = lp - 32; }
  const float* sp = src + ((size_t)pl << 16);
  const int c = t >> 2, g = t & 3;
  #pragma unroll
  for (int i = 0; i < 4; ++i)
    *(float4*)&T[c][(g<<4)+(i<<2)] = *(const float4*)(sp + ((size_t)c << 10) + p0 + (g<<4) + (i<<2));
  __syncthreads();
  const int p = t >> 2, c0 = (t & 3) << 4;
  uint w4[8];
  #pragma unroll
  for (int k = 0; k < 8; ++k)
    w4[k] = (uint)f2b(T[c0+2*k][p]) | ((uint)f2b(T[c0+2*k+1][p]) << 16);
  ushort* dst = outT + ((((size_t)pl << 10) + p0 + p) << 6) + c0;
  *(uint4*)(dst)     = *(uint4*)&w4[0];
  *(uint4*)(dst + 8) = *(uint4*)&w4[4];
}

// ---------------------------------------------------------------------------
// Mega-prep 2 (after gates): o/sa/ca weight pack + chist->kvC/kvT +
// ft->ftC/qT + memo m-half -> memoT[b][px][128] (+64 offset).
// Blocks 0..1599: weights.  1600..3135: 96 plane jobs x16 p0-blocks.
// ---------------------------------------------------------------------------
__global__ __launch_bounds__(256) void k_postgates(
    const float* __restrict__ wO, ushort* __restrict__ dO,
    const float* __restrict__ wSA, ushort* __restrict__ dSA,
    const float* __restrict__ wCA, ushort* __restrict__ dCA,
    const float* __restrict__ chist, ushort* __restrict__ kvC, ushort* __restrict__ kvT,
    const float* __restrict__ ft, ushort* __restrict__ ftC, ushort* __restrict__ qT,
    const float* __restrict__ memo, ushort* __restrict__ memoT)
{
  const int bid = blockIdx.x, t = threadIdx.x;
  __shared__ __align__(16) float T[64][68];
  if (bid < 1600){
    int idx = bid*256 + t;
    const float* s; ushort* d; int Co, Ci;
    if (idx < 204800){ s=wO; d=dO; Co=64; Ci=128; }
    else if ((idx -= 204800) < 102400){ s=wSA; d=dSA; Co=64; Ci=64; }
    else if ((idx -= 102400) < 102400){ s=wCA; d=dCA; Co=64; Ci=64; }
    else return;
    int ci = idx % Ci; int r = idx / Ci; int co = r % Co; int tap = r / Co;
    d[idx] = f2b(s[((size_t)(co*Ci + ci))*25 + tap]);
    return;
  }
  const int j = bid - 1600;
  const int p0 = (j & 15) << 6;
  const int lp = j >> 4;                 // 0..95
  const int c = t >> 2, g = t & 3;
  if (lp < 80){
    const float* src; ushort* outC; ushort* outT; int pl;
    if (lp < 64){ src = chist; outC = kvC; outT = kvT; pl = lp; }
    else { src = ft; outC = ftC; outT = qT; pl = lp - 64; }
    const float* sp = src + ((size_t)pl << 16);
    #pragma unroll
    for (int i = 0; i < 4; ++i){
      float4 f = *(const float4*)(sp + ((size_t)c << 10) + p0 + (g<<4) + (i<<2));
      *(float4*)&T[c][(g<<4)+(i<<2)] = f;
      uint2 pk2;
      pk2.x = (uint)f2b(f.x) | ((uint)f2b(f.y) << 16);
      pk2.y = (uint)f2b(f.z) | ((uint)f2b(f.w) << 16);
      *(uint2*)(outC + ((((size_t)pl << 6) + c) << 10) + p0 + (g<<4) + (i<<2)) = pk2;
    }
    __syncthreads();
    const int p = t >> 2, c0 = (t & 3) << 4;
    uint w4[8];
    #pragma unroll
    for (int k = 0; k < 8; ++k)
      w4[k] = (uint)f2b(T[c0+2*k][p]) | ((uint)f2b(T[c0+2*k+1][p]) << 16);
    ushort* dst = outT + ((((size_t)pl << 10) + p0 + p) << 6) + c0;
    *(uint4*)(dst)     = *(uint4*)&w4[0];
    *(uint4*)(dst + 8) = *(uint4*)&w4[4];
  } else {
    const int b = lp - 80;               // memo m-half plane
    const float* sp = memo + ((size_t)(b*2 + 1) << 16);
    #pragma unroll
    for (int i = 0; i < 4; ++i)
      *(float4*)&T[c][(g<<4)+(i<<2)] = *(const float4*)(sp + ((size_t)c << 10) + p0 + (g<<4) + (i<<2));
    __syncthreads();
    const int p = t >> 2, c0 = (t & 3) << 4;
    uint w4[8];
    #pragma unroll
    for (int k = 0; k < 8; ++k)
      w4[k] = (uint)f2b(T[c0+2*k][p]) | ((uint)f2b(T[c0+2*k+1][p]) << 16);
    ushort* dst = memoT + ((((size_t)b << 10) + p0 + p) << 7) + 64 + c0;
    *(uint4*)(dst)     = *(uint4*)&w4[0];
    *(uint4*)(dst + 8) = *(uint4*)&w4[4];
  }
}

// ---------------------------------------------------------------------------
// Generic transpose prep with LayerNorm (for sp/ch after attention).
// ---------------------------------------------------------------------------
struct PT { const float* s; ushort* d; const float* st; const float* g; const float* bb; };

__global__ __launch_bounds__(256) void k_prepT3(PT ja, PT jb, PT jc, int n0, int n1, float invN)
{
  const int lp = blockIdx.y;
  PT j; int pl;
  if (lp < n0){ j = ja; pl = lp; }
  else if (lp < n0 + n1){ j = jb; pl = lp - n0; }
  else { j = jc; pl = lp - n0 - n1; }
  const float* sp = j.s + ((size_t)pl << 16);
  float mean = 0.f, rstd = 0.f;
  if (j.st){
    float s0 = j.st[pl*2], s1 = j.st[pl*2+1];
    mean = s0*invN; rstd = rsqrtf(s1*invN - mean*mean + 1e-5f);
  }
  const int p0 = blockIdx.x << 6;
  __shared__ __align__(16) float T[64][68];
  const int t = threadIdx.x, c = t >> 2, g4 = t & 3;
  #pragma unroll
  for (int i = 0; i < 4; ++i){
    const int px = (g4 << 4) + (i << 2);
    float4 f = *(const float4*)(sp + ((size_t)c << 10) + p0 + px);
    if (j.st){
      const size_t li = ((size_t)c << 10) + p0 + px;
      float4 gv = *(const float4*)(j.g + li);
      float4 bv = *(const float4*)(j.bb + li);
      f.x = (f.x - mean)*rstd*gv.x + bv.x;
      f.y = (f.y - mean)*rstd*gv.y + bv.y;
      f.z = (f.z - mean)*rstd*gv.z + bv.z;
      f.w = (f.w - mean)*rstd*gv.w + bv.w;
    }
    *(float4*)&T[c][px] = f;
  }
  __syncthreads();
  const int p = t >> 2, c0 = (t & 3) << 4;
  uint w4[8];
  #pragma unroll
  for (int k = 0; k < 8; ++k){
    ushort lo = f2b(T[c0 + 2*k][p]);
    ushort hi = f2b(T[c0 + 2*k + 1][p]);
    w4[k] = (uint)lo | ((uint)hi << 16);
  }
  ushort* dst = j.d + ((((size_t)pl << 10) + p0 + p) << 6) + c0;
  *(uint4*)(dst)     = *(uint4*)&w4[0];
  *(uint4*)(dst + 8) = *(uint4*)&w4[4];
}

// ---------------------------------------------------------------------------
// Fused multi-segment MFMA 5x5 SAME conv.  Round-7 staging/layouts, but W
// staged into a SINGLE LDS buffer (one dy-row), restaged between two barriers
// per dy with register prefetch issued a full MFMA phase ahead.
// LDS: MT=4 48.1 KB -> 3 blocks/CU; MT=2 37.9 KB -> 4 blocks/CU.
// ---------------------------------------------------------------------------
struct Seg {
  const ushort* inT; const ushort* w; const float* bias;
  float* out; float* ostat;
  int Cin, Cout;
};
struct Segs3 { Seg s[3]; int b1, b2; };

template<int MT, int RPB>
__global__ __launch_bounds__(256, MT==4 ? 3 : 4) void k_convX(Segs3 Sg)
{
  constexpr int CO   = MT*16;
  constexpr int NW   = 5*CO*4;                 // uint4 units per dy-group
  constexpr int ITW  = (NW + 255) / 256;
  constexpr int DXSH = (MT == 4 ? 8 : 7);      // u >> DXSH = dx
  constexpr int PXB  = 32/RPB;                 // pixel-blocks per image
  constexpr int ROWS = RPB + 4;
  constexpr int RPW  = RPB/4;                  // rows per wave
  constexpr int NTIL = RPB/2;                  // 16-px n-tiles per wave
  constexpr int SUN2 = ROWS*36;

  const int b = blockIdx.y;
  const int cog = blockIdx.x / PXB, pxblk = blockIdx.x % PXB;
  const int si = (cog >= Sg.b1) + (cog >= Sg.b2);
  const Seg sg = Sg.s[si];
  const int base = si == 0 ? 0 : (si == 1 ? Sg.b1 : Sg.b2);
  const int co0 = (cog - base) * CO;
  const int r0 = pxblk * RPB;
  const int t = threadIdx.x, w = t >> 6, l = t & 63;
  const int lane16 = l & 15, quad = l >> 4;

  __shared__ __align__(16) ushort S_[4][ROWS][36][8];  // input [ci-quad][row][col][8ci]
  __shared__ __align__(16) ushort W_[NW*8];            // single dy-row of weights

  f4v acc[MT][NTIL];
  #pragma unroll
  for (int mi = 0; mi < MT; ++mi)
    #pragma unroll
    for (int n = 0; n < NTIL; ++n) acc[mi][n] = (f4v){0.f,0.f,0.f,0.f};

  size_t woff0[ITW];
  #pragma unroll
  for (int it = 0; it < ITW; ++it){
    const int u = t + it*256;
    const int l16u = u & 15, qu = (u >> 4) & 3;
    const int miu = (u >> 6) & (MT - 1), dxu = u >> DXSH;
    woff0[it] = ((size_t)(dxu*sg.Cout + co0 + miu*16 + l16u))*sg.Cin + (qu << 3);
  }
  const size_t wdy = (size_t)5 * sg.Cout * sg.Cin;   // one dy-row of taps

  uint4 wreg[ITW];
  auto loadW = [&](int cc_, int dy_){
    #pragma unroll
    for (int it = 0; it < ITW; ++it){
      const int u = t + it*256;
      if (ITW*256 == NW || u < NW)
        wreg[it] = *(const uint4*)(sg.w + woff0[it] + (size_t)dy_*wdy + (cc_ << 5));
    }
  };
  auto writeW = [&](){
    #pragma unroll
    for (int it = 0; it < ITW; ++it){
      const int u = t + it*256;
      if (ITW*256 == NW || u < NW)
        *(uint4*)&W_[(size_t)u * 8] = wreg[it];
    }
  };

  const int ncc = sg.Cin >> 5;
  loadW(0, 0);
  for (int cc = 0; cc < ncc; ++cc){
    __syncthreads();                     // prior S_/W_ readers done
    // ---- stage input stripe: rows r0-2..r0+RPB+1, cols -2..33, 32 ci ----
    for (int idx = t; idx < SUN2; idx += 256){
      const int row = idx / 36, col = idx - row*36;
      const int ir = r0 - 2 + row, ic = col - 2;
      uint4 pk[4] = {make_uint4(0,0,0,0),make_uint4(0,0,0,0),make_uint4(0,0,0,0),make_uint4(0,0,0,0)};
      if ((unsigned)ir < 32u && (unsigned)ic < 32u){
        const ushort* bp = sg.inT + ((size_t)((b << 10) + (ir << 5) + ic)) * sg.Cin + (cc << 5);
        #pragma unroll
        for (int q = 0; q < 4; ++q) pk[q] = *(const uint4*)(bp + (q << 3));
      }
      #pragma unroll
      for (int q = 0; q < 4; ++q) *(uint4*)&S_[q][row][col][0] = pk[q];
    }
    writeW();                            // W(cc, 0)
    loadW(cc, 1);
    __syncthreads();
    #pragma unroll
    for (int dy = 0; dy < 5; ++dy){
      #pragma unroll
      for (int dx = 0; dx < 5; ++dx){
        s8v a[MT];
        #pragma unroll
        for (int mi = 0; mi < MT; ++mi){
          const int au = ((((dx*MT + mi) << 2) + quad) << 4) + lane16;
          a[mi] = *(const s8v*)&W_[au << 3];
        }
        #pragma unroll
        for (int n = 0; n < NTIL; ++n){
          const int srow = w*RPW + (n >> 1) + dy;
          const int col = ((n & 1) << 4) + lane16 + dx;
          s8v bb = *(const s8v*)&S_[quad][srow][col][0];
          #pragma unroll
          for (int mi = 0; mi < MT; ++mi)
            acc[mi][n] = __builtin_amdgcn_mfma_f32_16x16x32_bf16(a[mi], bb, acc[mi][n], 0, 0, 0);
        }
      }
      if (dy < 4){
        __syncthreads();                 // W_ readers of dy done
        writeW();                        // W(cc, dy+1)
        if (dy < 3) loadW(cc, dy + 2);
        else if (cc + 1 < ncc) loadW(cc + 1, 0);
        __syncthreads();                 // W_ (dy+1) visible
      }
    }
  }
  // ---- epilogue ----
  float lsum = 0.f, lsq = 0.f;
  #pragma unroll
  for (int mi = 0; mi < MT; ++mi){
    const int co = co0 + mi*16 + (quad << 2);
    #pragma unroll
    for (int n = 0; n < NTIL; ++n){
      const int row = r0 + w*RPW + (n >> 1);
      const int col = ((n & 1) << 4) + lane16;
      #pragma unroll
      for (int i = 0; i < 4; ++i){
        float v = acc[mi][n][i] + (sg.bias ? sg.bias[co+i] : 0.f);
        sg.out[(((size_t)(b*sg.Cout + co + i)) << 10) + (row << 5) + col] = v;
        lsum += v; lsq += v*v;
      }
    }
  }
  if (sg.ostat) red_atomic2(lsum, lsq, sg.ostat, b, t);
}

// ---------------------------------------------------------------------------
// Gates
// ---------------------------------------------------------------------------
__global__ __launch_bounds__(256) void k_gates(
    const float* __restrict__ bufx, const float* __restrict__ bufh, const float* __restrict__ bufm,
    const float* __restrict__ lnxg, const float* __restrict__ lnxb,
    const float* __restrict__ lnhg, const float* __restrict__ lnhb,
    const float* __restrict__ lnmg, const float* __restrict__ lnmb,
    const float* __restrict__ m_t, const float* __restrict__ stats,
    float* __restrict__ ft, float* __restrict__ ig, float* __restrict__ osum,
    float* __restrict__ memo, float* __restrict__ out_m)
{
  const int idx = blockIdx.x*256 + threadIdx.x;
  const int b = idx >> 16, rem = idx & 65535;
  const int c = rem >> 10, p = rem & 1023;

  float mx = stats[b*2]      * (1.f/458752.f);
  float vx = stats[b*2+1]    * (1.f/458752.f) - mx*mx;  float rx = rsqrtf(vx + 1e-5f);
  float mh = stats[32+b*2]   * (1.f/262144.f);
  float vh = stats[32+b*2+1] * (1.f/262144.f) - mh*mh;  float rh = rsqrtf(vh + 1e-5f);
  float mm = stats[64+b*2]   * (1.f/196608.f);
  float vm = stats[64+b*2+1] * (1.f/196608.f) - mm*mm;  float rm = rsqrtf(vm + 1e-5f);

  auto LX = [&](int k){
    size_t ch = (size_t)k*64 + c; size_t gi = ((size_t)b*448 + ch)*1024 + p; size_t li = ch*1024 + p;
    return (bufx[gi] - mx)*rx*lnxg[li] + lnxb[li]; };
  auto LH = [&](int k){
    size_t ch = (size_t)k*64 + c; size_t gi = ((size_t)b*256 + ch)*1024 + p; size_t li = ch*1024 + p;
    return (bufh[gi] - mh)*rh*lnhg[li] + lnhb[li]; };
  auto LM = [&](int k){
    size_t ch = (size_t)k*64 + c; size_t gi = ((size_t)b*192 + ch)*1024 + p; size_t li = ch*1024 + p;
    return (bufm[gi] - mm)*rm*lnmg[li] + lnmb[li]; };

  float i_t = sigm(LX(0) + LH(0));
  float f_t = sigm(LX(1) + LH(1) + 1.f);
  float g_t = tanh_(LX(2) + LH(2));
  float i_p = sigm(LX(3) + LM(0));
  float f_p = sigm(LX(4) + LM(1) + 1.f);
  float g_p = tanh_(LX(5) + LM(2));
  float ox = LX(6), oh = LH(3);

  ft[idx]   = f_t;
  ig[idx]   = i_t * g_t;
  osum[idx] = ox + oh;
  float mn = f_p * m_t[idx] + i_p * g_p;
  out_m[idx] = mn;
  memo[((size_t)(b*128 + 64 + c) << 10) + p] = mn;
}

// ---------------------------------------------------------------------------
// Fused spatial attention (kv-split x2, additive num/den partials) and
// channel-attn logits.  Blocks 0..511: spat (p0,b,half).  512..639: chlog.
// LDS shared via char buffer (max = spat's 44288 B).
// ---------------------------------------------------------------------------
__global__ __launch_bounds__(256) void k_spat_chlog(
    const ushort* __restrict__ qT, const ushort* __restrict__ kvC, const ushort* __restrict__ kvT,
    float* __restrict__ num, float* __restrict__ den,
    const ushort* __restrict__ ftC, float* __restrict__ lg)
{
  __shared__ __align__(16) char smem[44288];
  const int bid = blockIdx.x, t = threadIdx.x;
  const int w = t >> 6, l = t & 63;
  const int lane16 = l & 15, quad = l >> 4;

  if (bid < 512){
    const int p0 = (bid & 15) << 6, b = (bid >> 4) & 15, half = bid >> 8;
    ushort (*Kt)[72] = reinterpret_cast<ushort(*)[72]>(smem);
    ushort (*Kc)[72] = reinterpret_cast<ushort(*)[72]>(smem + 9216);
    ushort (*Eb)[72] = reinterpret_cast<ushort(*)[72]>(smem + 18432);
    float  (*XO)[65] = reinterpret_cast<float(*)[65]>(smem + 27648);

    s8v qa0, qa1;
    {
      const ushort* qr = qT + ((((size_t)b << 10) + p0 + (w << 4) + lane16) << 6) + (quad << 3);
      qa0 = *(const s8v*)(qr);
      qa1 = *(const s8v*)(qr + 32);
    }
    f4v o0 = {0.f,0.f,0.f,0.f}, o1 = o0, o2 = o0, o3 = o0, dacc = o0;
    const short oneb = (short)0x3F80;
    const s8v ones = { oneb, oneb, oneb, oneb, oneb, oneb, oneb, oneb };

    const int r = t >> 2, g4 = (t & 3) << 4;
    for (int ck = 0; ck < 32; ++ck){
      const int chunk = (half << 5) + ck;
      const int lidx = chunk >> 4, pk = (chunk & 15) << 6;
      __syncthreads();
      {
        const ushort* sc = kvC + ((((size_t)(b*4 + lidx) << 6) + r) << 10) + pk + g4;
        *(uint4*)&Kc[r][g4]     = *(const uint4*)(sc);
        *(uint4*)&Kc[r][g4 + 8] = *(const uint4*)(sc + 8);
        const ushort* st = kvT + ((((size_t)(b*4 + lidx) << 10) + pk + r) << 6) + g4;
        *(uint4*)&Kt[r][g4]     = *(const uint4*)(st);
        *(uint4*)&Kt[r][g4 + 8] = *(const uint4*)(st + 8);
      }
      __syncthreads();
      #pragma unroll
      for (int nt = 0; nt < 4; ++nt){
        const ushort* bt = &Kt[(nt << 4) + lane16][quad << 3];
        s8v b0 = *(const s8v*)(bt);
        s8v b1 = *(const s8v*)(bt + 32);
        f4v s = {0.f,0.f,0.f,0.f};
        s = __builtin_amdgcn_mfma_f32_16x16x32_bf16(qa0, b0, s, 0, 0, 0);
        s = __builtin_amdgcn_mfma_f32_16x16x32_bf16(qa1, b1, s, 0, 0, 0);
        #pragma unroll
        for (int i = 0; i < 4; ++i){
          float e = __expf(s[i] - 12.f);
          Eb[(w << 4) + (quad << 2) + i][(nt << 4) + lane16] = f2b(e);
        }
      }
      __syncthreads();
      #pragma unroll
      for (int ks = 0; ks < 2; ++ks){
        s8v ea = *(const s8v*)&Eb[(w << 4) + lane16][(ks << 5) + (quad << 3)];
        dacc = __builtin_amdgcn_mfma_f32_16x16x32_bf16(ea, ones, dacc, 0, 0, 0);
        s8v bc0 = *(const s8v*)&Kc[ 0 + lane16][(ks << 5) + (quad << 3)];
        s8v bc1 = *(const s8v*)&Kc[16 + lane16][(ks << 5) + (quad << 3)];
        s8v bc2 = *(const s8v*)&Kc[32 + lane16][(ks << 5) + (quad << 3)];
        s8v bc3 = *(const s8v*)&Kc[48 + lane16][(ks << 5) + (quad << 3)];
        o0 = __builtin_amdgcn_mfma_f32_16x16x32_bf16(ea, bc0, o0, 0, 0, 0);
        o1 = __builtin_amdgcn_mfma_f32_16x16x32_bf16(ea, bc1, o1, 0, 0, 0);
        o2 = __builtin_amdgcn_mfma_f32_16x16x32_bf16(ea, bc2, o2, 0, 0, 0);
        o3 = __builtin_amdgcn_mfma_f32_16x16x32_bf16(ea, bc3, o3, 0, 0, 0);
      }
    }
    {
      const int pxl = (w << 4) + (quad << 2);
      if (lane16 == 0){
        float* dp = den + (((size_t)(half*16 + b)) << 10) + p0 + pxl;
        dp[0] = dacc[0]; dp[1] = dacc[1]; dp[2] = dacc[2]; dp[3] = dacc[3];
      }
      XO[ 0 + lane16][pxl+0] = o0[0]; XO[ 0 + lane16][pxl+1] = o0[1];
      XO[ 0 + lane16][pxl+2] = o0[2]; XO[ 0 + lane16][pxl+3] = o0[3];
      XO[16 + lane16][pxl+0] = o1[0]; XO[16 + lane16][pxl+1] = o1[1];
      XO[16 + lane16][pxl+2] = o1[2]; XO[16 + lane16][pxl+3] = o1[3];
      XO[32 + lane16][pxl+0] = o2[0]; XO[32 + lane16][pxl+1] = o2[1];
      XO[32 + lane16][pxl+2] = o2[2]; XO[32 + lane16][pxl+3] = o2[3];
      XO[48 + lane16][pxl+0] = o3[0]; XO[48 + lane16][pxl+1] = o3[1];
      XO[48 + lane16][pxl+2] = o3[2]; XO[48 + lane16][pxl+3] = o3[3];
    }
    __syncthreads();
    {
      const int ch = t >> 2;
      float* nout = num + (size_t)half * N1;
      #pragma unroll
      for (int i = 0; i < 4; ++i){
        size_t gi = ((size_t)b << 16) + ((size_t)ch << 10) + p0 + g4 + (i << 2);
        float4 ov;
        ov.x = XO[ch][g4 + (i << 2) + 0];
        ov.y = XO[ch][g4 + (i << 2) + 1];
        ov.z = XO[ch][g4 + (i << 2) + 2];
        ov.w = XO[ch][g4 + (i << 2) + 3];
        *(float4*)(nout + gi) = ov;
      }
    }
  } else {
    const int j = bid - 512;
    const int bx = j & 7, b = j >> 3;
    const int np = bx >> 1, mp = bx & 1;
    ushort (*As)[32][8] = reinterpret_cast<ushort(*)[32][8]>(smem);
    ushort (*Bs)[64][8] = reinterpret_cast<ushort(*)[64][8]>(smem + 4096);
    f4v acc[2];
    acc[0] = (f4v){0.f,0.f,0.f,0.f}; acc[1] = (f4v){0.f,0.f,0.f,0.f};

    for (int kc = 0; kc < 16; ++kc){
      __syncthreads();
      {
        const int c = t >> 3, q = t & 7;
        *(uint4*)&As[q][c][0] = *(const uint4*)(ftC + (((size_t)(b*64 + mp*32 + c)) << 10) + (kc<<6) + (q<<3));
      }
      #pragma unroll
      for (int it = 0; it < 2; ++it){
        const int idx = t + it*256;
        const int r2 = idx >> 3, q = idx & 7;
        *(uint4*)&Bs[q][r2][0] = *(const uint4*)(kvC + ((((size_t)(b*4 + np) << 6) + r2) << 10) + (kc<<6) + (q<<3));
      }
      __syncthreads();
      #pragma unroll
      for (int ks = 0; ks < 2; ++ks){
        s8v a0 = *(const s8v*)&As[(ks<<2)+quad][lane16][0];
        s8v a1 = *(const s8v*)&As[(ks<<2)+quad][16 + lane16][0];
        s8v bb = *(const s8v*)&Bs[(ks<<2)+quad][(w<<4) + lane16][0];
        acc[0] = __builtin_amdgcn_mfma_f32_16x16x32_bf16(a0, bb, acc[0], 0, 0, 0);
        acc[1] = __builtin_amdgcn_mfma_f32_16x16x32_bf16(a1, bb, acc[1], 0, 0, 0);
      }
    }
    #pragma unroll
    for (int mi = 0; mi < 2; ++mi)
      #pragma unroll
      for (int i = 0; i < 4; ++i){
        const int c = mp*32 + mi*16 + (quad<<2) + i;
        const int n = (np<<6) + (w<<4) + lane16;
        lg[(((size_t)(b*64 + c)) << 8) + n] = acc[mi][i];
      }
  }
}

// ---------------------------------------------------------------------------
// Fused channel-softmax (blocks 0..255) and spatial combine (256..511).
// ---------------------------------------------------------------------------
__global__ __launch_bounds__(256) void k_chsm_spcomb(
    const float* __restrict__ a, ushort* __restrict__ ab,
    const float* __restrict__ num, const float* __restrict__ den,
    const float* __restrict__ c_t, float* __restrict__ sp_raw, float* __restrict__ stats)
{
  const int bid = blockIdx.x, t = threadIdx.x;
  if (bid < 256){
    const int row  = bid*4 + (t >> 6);
    const int lane = t & 63;
    const float* rp = a + ((size_t)row << 8);
    float v0 = rp[lane], v1 = rp[lane+64], v2 = rp[lane+128], v3 = rp[lane+192];
    float mx = fmaxf(fmaxf(v0, v1), fmaxf(v2, v3));
    #pragma unroll
    for (int m = 32; m; m >>= 1) mx = fmaxf(mx, __shfl_xor(mx, m));
    v0 = __expf(v0 - mx); v1 = __expf(v1 - mx); v2 = __expf(v2 - mx); v3 = __expf(v3 - mx);
    float s = v0 + v1 + v2 + v3;
    #pragma unroll
    for (int m = 32; m; m >>= 1) s += __shfl_xor(s, m);
    float inv = 1.f / s;
    ushort* op = ab + ((size_t)row << 8);
    op[lane] = f2b(v0*inv); op[lane+64] = f2b(v1*inv);
    op[lane+128] = f2b(v2*inv); op[lane+192] = f2b(v3*inv);
  } else {
    const int j = bid - 256;
    const int p0 = (j & 15) << 6, b = j >> 4;
    const int ch = t >> 2, g4 = (t & 3) << 4;
    float lsum = 0.f, lsq = 0.f;
    #pragma unroll
    for (int i = 0; i < 4; ++i){
      const int px = p0 + g4 + (i << 2);
      size_t gi = ((size_t)b << 16) + ((size_t)ch << 10) + px;
      float4 n0 = *(const float4*)(num + gi);
      float4 n1 = *(const float4*)(num + (size_t)N1 + gi);
      const float* d0 = den + (((size_t)b) << 10) + px;
      const float* d1 = den + (((size_t)(16 + b)) << 10) + px;
      float4 cv = *(const float4*)(c_t + gi);
      float4 ov;
      ov.x = cv.x + (n0.x + n1.x) / (d0[0] + d1[0]);
      ov.y = cv.y + (n0.y + n1.y) / (d0[1] + d1[1]);
      ov.z = cv.z + (n0.z + n1.z) / (d0[2] + d1[2]);
      ov.w = cv.w + (n0.w + n1.w) / (d0[3] + d1[3]);
      *(float4*)(sp_raw + gi) = ov;
      lsum += ov.x + ov.y + ov.z + ov.w;
      lsq  += ov.x*ov.x + ov.y*ov.y + ov.z*ov.z + ov.w*ov.w;
    }
    red_atomic2(lsum, lsq, stats, b, t);
  }
}

// ---------------------------------------------------------------------------
// Channel attention output via MFMA.  Grid (16,16): 64-px chunks.
// ---------------------------------------------------------------------------
__global__ __launch_bounds__(256) void k_chout_m(
    const ushort* __restrict__ chlb, const ushort* __restrict__ kvT,
    const float* __restrict__ c_t, float* __restrict__ ch_raw, float* __restrict__ stats)
{
  const int p0 = blockIdx.x << 6, b = blockIdx.y;
  const int t = threadIdx.x, w = t >> 6, l = t & 63;
  const int lane16 = l & 15, quad = l >> 4;
  __shared__ __align__(16) ushort As[32][64][8];
  __shared__ __align__(16) ushort Bs[32][32][8];
  #pragma unroll
  for (int it = 0; it < 8; ++it){
    const int idx = t + it*256;
    const int c = idx >> 5, q = idx & 31;
    *(uint4*)&As[q][c][0] = *(const uint4*)(chlb + (((size_t)(b*64 + c)) << 8) + (q<<3));
  }
  __syncthreads();
  s8v a[8];
  #pragma unroll
  for (int ks = 0; ks < 8; ++ks)
    a[ks] = *(const s8v*)&As[(ks<<2)+quad][(w<<4) + lane16][0];
  float lsum = 0.f, lsq = 0.f;
  for (int pc = 0; pc < 2; ++pc){
    __syncthreads();
    #pragma unroll
    for (int it = 0; it < 4; ++it){
      const int idx = t + it*256;
      const int px = idx >> 5, q = idx & 31;
      const int plane = (b<<2) + (q>>3);
      *(uint4*)&Bs[q][px][0] = *(const uint4*)(kvT + ((((size_t)plane << 10) + p0 + (pc<<5) + px) << 6) + ((q&7)<<3));
    }
    __syncthreads();
    #pragma unroll
    for (int nt = 0; nt < 2; ++nt){
      f4v o = {0.f,0.f,0.f,0.f};
      #pragma unroll
      for (int ks = 0; ks < 8; ++ks){
        s8v bb = *(const s8v*)&Bs[(ks<<2)+quad][(nt<<4) + lane16][0];
        o = __builtin_amdgcn_mfma_f32_16x16x32_bf16(a[ks], bb, o, 0, 0, 0);
      }
      #pragma unroll
      for (int i = 0; i < 4; ++i){
        const int c = (w<<4) + (quad<<2) + i;
        const int px = p0 + (pc<<5) + (nt<<4) + lane16;
        size_t gi = ((size_t)b << 16) + ((size_t)c << 10) + px;
        float v = c_t[gi] + o[i];
        ch_raw[gi] = v;
        lsum += v; lsq += v*v;
      }
    }
  }
  red_atomic2(lsum, lsq, stats, b, t);
}

// ---------------------------------------------------------------------------
// LN+relu both attention branches, 1x1 convs, sum, 1x1 attn_w, c_new.
// Also writes the bf16-transposed c-half of memoT (replaces prepTm).
// ---------------------------------------------------------------------------
__global__ __launch_bounds__(256) void k_attnfinal(
    const float* __restrict__ samid, const float* __restrict__ camid,
    const float* __restrict__ stats_sa, const float* __restrict__ stats_ca,
    const float* __restrict__ salng, const float* __restrict__ salnb,
    const float* __restrict__ calng, const float* __restrict__ calnb,
    const float* __restrict__ wsa2, const float* __restrict__ wca2,
    const float* __restrict__ cab2, const float* __restrict__ wat,
    const float* __restrict__ ig, float* __restrict__ out_c, float* __restrict__ memo,
    ushort* __restrict__ memoT)
{
  const int p0 = blockIdx.x << 6, b = blockIdx.y, t = threadIdx.x;
  const int tc = t & 15, tp = t >> 4;
  __shared__ __align__(16) float R[64][68];
  __shared__ __align__(16) float Wl[64][68];
  __shared__ __align__(16) float Ms[64][68];
  const float invN = 1.f/65536.f;
  float acc[4][4] = {};
  #pragma unroll
  for (int pass = 0; pass < 2; ++pass){
    const float* mid = pass ? camid : samid;
    const float* st  = pass ? stats_ca : stats_sa;
    const float* g   = pass ? calng : salng;
    const float* bb  = pass ? calnb : salnb;
    const float* w   = pass ? wca2  : wsa2;
    float mean = st[b*2]*invN;
    float var  = st[b*2+1]*invN - mean*mean;
    float rstd = rsqrtf(var + 1e-5f);
    __syncthreads();
    {
      const int j = t & 63, c0 = t >> 6;
      for (int ci = c0; ci < 64; ci += 4){
        size_t gi = ((size_t)b << 16) + ((size_t)ci << 10) + p0 + j;
        size_t li = ((size_t)ci << 10) + p0 + j;
        float v = (mid[gi] - mean)*rstd*g[li] + bb[li];
        R[ci][j] = fmaxf(v, 0.f);
      }
      const int ci2 = t & 63, c20 = t >> 6;
      for (int c2 = c20; c2 < 64; c2 += 4) Wl[ci2][c2] = w[((size_t)c2 << 6) + ci2];
    }
    __syncthreads();
    for (int ci = 0; ci < 64; ++ci){
      float wv[4], rv[4];
      *(float4*)wv = *(const float4*)&Wl[ci][4*tc];
      *(float4*)rv = *(const float4*)&R[ci][4*tp];
      #pragma unroll
      for (int i = 0; i < 4; ++i)
        #pragma unroll
        for (int j = 0; j < 4; ++j)
          acc[i][j] = fmaf(wv[i], rv[j], acc[i][j]);
    }
  }
  {
    float b2[4];
    #pragma unroll
    for (int i = 0; i < 4; ++i) b2[i] = cab2[4*tc + i];
    #pragma unroll
    for (int i = 0; i < 4; ++i)
      #pragma unroll
      for (int j = 0; j < 4; ++j)
        Ms[4*tc+i][4*tp+j] = acc[i][j] + b2[i];
  }
  __syncthreads();
  {
    const int ci2 = t & 63, c20 = t >> 6;
    for (int c2 = c20; c2 < 64; c2 += 4) Wl[ci2][c2] = wat[((size_t)c2 << 6) + ci2];
  }
  __syncthreads();
  float acc2[4][4] = {};
  for (int c2 = 0; c2 < 64; ++c2){
    float wv[4], mv[4];
    *(float4*)wv = *(const float4*)&Wl[c2][4*tc];
    *(float4*)mv = *(const float4*)&Ms[c2][4*tp];
    #pragma unroll
    for (int i = 0; i < 4; ++i)
      #pragma unroll
      for (int j = 0; j < 4; ++j)
        acc2[i][j] = fmaf(wv[i], mv[j], acc2[i][j]);
  }
  float vv[4][4];
  #pragma unroll
  for (int i = 0; i < 4; ++i)
    #pragma unroll
    for (int j = 0; j < 4; ++j){
      size_t gi = ((size_t)b << 16) + ((size_t)(4*tc + i) << 10) + p0 + 4*tp + j;
      float v = acc2[i][j] + ig[gi];
      vv[i][j] = v;
      out_c[gi] = v;
      memo[((size_t)(b*128 + 4*tc + i) << 10) + p0 + 4*tp + j] = v;
    }
  #pragma unroll
  for (int j = 0; j < 4; ++j){
    uint2 pk;
    pk.x = (uint)f2b(vv[0][j]) | ((uint)f2b(vv[1][j]) << 16);
    pk.y = (uint)f2b(vv[2][j]) | ((uint)f2b(vv[3][j]) << 16);
    *(uint2*)(memoT + ((((size_t)b << 10) + p0 + 4*tp + j) << 7) + 4*tc) = pk;
  }
}

// ---------------------------------------------------------------------------
__global__ __launch_bounds__(256) void k_final(
    const float* __restrict__ memo, const float* __restrict__ wlast,
    const float* __restrict__ bufo, const float* __restrict__ osum,
    const float* __restrict__ stats_o, const float* __restrict__ lnog, const float* __restrict__ lnob,
    float* __restrict__ out_h)
{
  const int p0 = blockIdx.x << 6, b = blockIdx.y, t = threadIdx.x;
  const int tc = t & 15, tp = t >> 4;
  __shared__ __align__(16) float Msh[64][68];
  __shared__ __align__(16) float Wt[64][68];
  float acc[4][4] = {};
  #pragma unroll
  for (int half = 0; half < 2; ++half){
    __syncthreads();
    {
      const int j = t & 63, c0 = t >> 6;
      for (int ci = c0; ci < 64; ci += 4)
        Msh[ci][j] = memo[((size_t)(b*128 + half*64 + ci) << 10) + p0 + j];
      const int ci2 = t & 63, co0 = t >> 6;
      for (int co = co0; co < 64; co += 4) Wt[ci2][co] = wlast[((size_t)co << 7) + half*64 + ci2];
    }
    __syncthreads();
    for (int ci = 0; ci < 64; ++ci){
      float wv[4], mv[4];
      *(float4*)wv = *(const float4*)&Wt[ci][4*tc];
      *(float4*)mv = *(const float4*)&Msh[ci][4*tp];
      #pragma unroll
      for (int i = 0; i < 4; ++i)
        #pragma unroll
        for (int j = 0; j < 4; ++j)
          acc[i][j] = fmaf(wv[i], mv[j], acc[i][j]);
    }
  }
  float mean = stats_o[b*2]*(1.f/65536.f);
  float var  = stats_o[b*2+1]*(1.f/65536.f) - mean*mean;
  float rstd = rsqrtf(var + 1e-5f);
  #pragma unroll
  for (int i = 0; i < 4; ++i)
    #pragma unroll
    for (int j = 0; j < 4; ++j){
      const int co = 4*tc + i, p = p0 + 4*tp + j;
      size_t gi = ((size_t)b << 16) + ((size_t)co << 10) + p;
      size_t li = ((size_t)co << 10) + p;
      float lno = (bufo[gi] - mean)*rstd*lnog[li] + lnob[li];
      float o = sigm(osum[gi] + lno);
      out_h[gi] = o * tanh_(acc[i][j]);
    }
}

// ---------------------------------------------------------------------------
extern "C" void kernel_launch(void* const* d_in, const int* in_sizes, int n_in,
                              void* d_out, int out_size, void* d_ws, size_t ws_size,
                              hipStream_t stream)
{
  const float* x_t   = (const float*)d_in[0];
  const float* h_t   = (const float*)d_in[1];
  const float* c_t   = (const float*)d_in[2];
  const float* chist = (const float*)d_in[3];
  const float* m_t   = (const float*)d_in[4];
  const float* w_x   = (const float*)d_in[5];
  const float* lnxg  = (const float*)d_in[6];
  const float* lnxb  = (const float*)d_in[7];
  const float* w_h   = (const float*)d_in[8];
  const float* lnhg  = (const float*)d_in[9];
  const float* lnhb  = (const float*)d_in[10];
  const float* w_m   = (const float*)d_in[11];
  const float* lnmg  = (const float*)d_in[12];
  const float* lnmb  = (const float*)d_in[13];
  const float* w_o   = (const float*)d_in[14];
  const float* lnog  = (const float*)d_in[15];
  const float* lnob  = (const float*)d_in[16];
  const float* w_last= (const float*)d_in[17];
  const float* sng   = (const float*)d_in[18];
  const float* snb   = (const float*)d_in[19];
  const float* cng   = (const float*)d_in[20];
  const float* cnb   = (const float*)d_in[21];
  const float* ca_w1 = (const float*)d_in[22];
  const float* ca_b1 = (const float*)d_in[23];
  const float* calng = (const float*)d_in[24];
  const float* calnb = (const float*)d_in[25];
  const float* ca_w2 = (const float*)d_in[26];
  const float* ca_b2 = (const float*)d_in[27];
  const float* sa_w1 = (const float*)d_in[28];
  const float* salng = (const float*)d_in[29];
  const float* salnb = (const float*)d_in[30];
  const float* sa_w2 = (const float*)d_in[31];
  const float* attn_w= (const float*)d_in[32];

  float* out = (float*)d_out;
  float* ws  = (float*)d_ws;

  float* stats = ws;                        // 8 groups x 16 batches x {sum,sumsq}
  float* bufx  = ws + 1024;                 // 7*N1 raw conv_x
  float* bufh  = bufx + 7*(size_t)N1;       // 4*N1
  float* bufm  = bufh + 4*(size_t)N1;       // 3*N1
  float* ft    = bufm + 3*(size_t)N1;       // N1
  float* ig    = ft   + (size_t)N1;         // N1
  float* osum  = ig   + (size_t)N1;         // N1
  float* memo  = osum + (size_t)N1;         // 2*N1
  // aliases valid AFTER k_gates consumed bufx/h/m:
  float* sp    = bufx;                      // N1 (spat num0, then sp in-place)
  float* ch    = bufx + (size_t)N1;         // N1 (spat num1 until spcomb, then ch)
  float* samid = bufx + 2*(size_t)N1;       // N1
  float* camid = bufx + 3*(size_t)N1;       // N1
  float* bufo  = bufx + 4*(size_t)N1;       // N1
  float* chl   = bufx + 5*(size_t)N1;       // channel-attn logits fp32 (1 MB)
  ushort* kvC  = (ushort*)bufh;             // 4M bf16 (8 MB)
  ushort* kvT  = kvC + 4*(size_t)N1;        // 4M bf16 (8 MB)
  ushort* qT   = (ushort*)bufm;             // N1 ushorts
  ushort* ftC  = qT + (size_t)N1;           // N1 ushorts

  // transposed bf16 conv inputs:
  ushort* xT   = (ushort*)memo;             // N1 ushorts (dead before k_gates)
  ushort* hT   = xT + (size_t)N1;
  ushort* mT   = hT + (size_t)N1;
  ushort* spT  = ftC + (size_t)N1;          // N1 ushorts
  ushort* chT  = spT + (size_t)N1;          // N1 ushorts
  ushort* memoT = chT + (size_t)N1;         // 2*N1 ushorts (bufm tail, exact fit)
  float*  numB = bufx;                      // spat partial numerators [2][N1] (sp/ch slots)

  // bf16 weights: xhm pack lives in ft region (free until k_gates writes it)
  ushort* wbx = (ushort*)ft;                // 716800
  ushort* wbh = wbx + 716800;               // 409600
  ushort* wbm = wbh + 409600;               // 307200
  // o/sa/ca pack + bf16 probs + spat den live after chl in bufx region
  ushort* wbo  = (ushort*)(chl + 262144);   // 204800
  ushort* wbsa = wbo + 204800;              // 102400
  ushort* wbca = wbsa + 102400;             // 102400
  ushort* chlb = wbca + 102400;             // 262144 (bf16 probs)
  float*  denP = chl + 600000;              // [2][16][1024] spat denominators

  float* out_h = out;
  float* out_c = out + (size_t)N1;
  float* out_m = out + 2*(size_t)N1;

  // 1) input-only prep: xhm weights + stats zero + x/h/m transpose
  k_pre<<<dim3(6368), dim3(256), 0, stream>>>(w_x, wbx, w_h, wbh, w_m, wbm,
                                              x_t, xT, h_t, hT, m_t, mT, stats);

  // 2) fused x+h+m MFMA conv (stats: x=0, h=32, m=64)
  {
    Segs3 XHM;
    XHM.s[0] = Seg{ xT, wbx, nullptr, bufx, stats+0,  64, 448 };
    XHM.s[1] = Seg{ hT, wbh, nullptr, bufh, stats+32, 64, 256 };
    XHM.s[2] = Seg{ mT, wbm, nullptr, bufm, stats+64, 64, 192 };
    XHM.b1 = 7; XHM.b2 = 11;
    k_convX<4,8><<<dim3(56,16), dim3(256), 0, stream>>>(XHM);
  }

  // 3) gates
  k_gates<<<dim3(4096), dim3(256), 0, stream>>>(bufx, bufh, bufm, lnxg, lnxb, lnhg, lnhb,
                                                lnmg, lnmb, m_t, stats,
                                                ft, ig, osum, memo, out_m);

  // 4) fused post-gates prep: o/sa/ca weights + chist/ft prep + memoT m-half
  k_postgates<<<dim3(3136), dim3(256), 0, stream>>>(w_o, wbo, sa_w1, wbsa, ca_w1, wbca,
                                                    chist, kvC, kvT, ft, ftC, qT,
                                                    memo, memoT);

  // 5) spatial attention (z2 partials) || channel logits
  k_spat_chlog<<<dim3(640), dim3(256), 0, stream>>>(qT, kvC, kvT, numB, denP, ftC, chl);

  // 6) channel softmax || spatial combine (stats: sp=96)
  k_chsm_spcomb<<<dim3(512), dim3(256), 0, stream>>>(chl, chlb, numB, denP, c_t, sp, stats+96);

  // 7) channel attention output (stats: ch=128)
  k_chout_m<<<dim3(16,16), dim3(256), 0, stream>>>(chlb, kvT, c_t, ch, stats+128);

  // 8) LN + transpose sp/ch -> bf16
  {
    PT js{ sp, spT, stats+96,  sng, snb };
    PT jc{ ch, chT, stats+128, cng, cnb };
    k_prepT3<<<dim3(16,32), dim3(256), 0, stream>>>(js, jc, js, 16, 16, 1.f/65536.f);
  }

  // 9) fused sa+ca 5x5 MFMA convs (stats: sa=160, ca=192)
  {
    Segs3 SC;
    SC.s[0] = Seg{ spT, wbsa, nullptr, samid, stats+160, 64, 64 };
    SC.s[1] = Seg{ chT, wbca, ca_b1,   camid, stats+192, 64, 64 };
    SC.s[2] = SC.s[1];
    SC.b1 = 2; SC.b2 = 1000;
    k_convX<2,8><<<dim3(16,16), dim3(256), 0, stream>>>(SC);
  }

  // 10) attn final (also writes memoT c-half)
  k_attnfinal<<<dim3(16,16), dim3(256), 0, stream>>>(samid, camid, stats+160, stats+192,
                                                     salng, salnb, calng, calnb,
                                                     sa_w2, ca_w2, ca_b2, attn_w,
                                                     ig, out_c, memo, memoT);

  // 11) conv_o over mem (Cin=128) (stats: o=224)
  {
    Segs3 O;
    O.s[0] = Seg{ memoT, wbo, nullptr, bufo, stats+224, 128, 64 };
    O.s[1] = O.s[0]; O.s[2] = O.s[0];
    O.b1 = 1000; O.b2 = 1000;
    k_convX<2,8><<<dim3(8,16), dim3(256), 0, stream>>>(O);
  }

  // 12) final
  k_final<<<dim3(16,16), dim3(256), 0, stream>>>(memo, w_last, bufo, osum, stats+224,
                                                 lnog, lnob, out_h);
}

// Round 11
// 470.304 us; speedup vs baseline: 1.0684x; 1.0684x over previous
//
#include <hip/hip_runtime.h>
#include <hip/hip_bf16.h>

#define N1 (1u << 20)   // B*NH*HW = 16*64*1024

typedef __attribute__((ext_vector_type(8))) short s8v;
typedef __attribute__((ext_vector_type(4))) float f4v;

static __device__ __forceinline__ float sigm(float x){ return 1.f/(1.f + __expf(-x)); }
static __device__ __forceinline__ float tanh_(float x){ return 1.f - 2.f/(__expf(2.f*x) + 1.f); }

static __device__ __forceinline__ ushort f2b(float f){
  union { float f; uint u; } x; x.f = f;
  uint r = x.u + 0x7FFFu + ((x.u >> 16) & 1u);
  return (ushort)(r >> 16);
}

static __device__ __forceinline__ void red_atomic2(float s, float q, float* d, int b, int t){
  #pragma unroll
  for (int m = 32; m; m >>= 1){ s += __shfl_xor(s, m); q += __shfl_xor(q, m); }
  if ((t & 63) == 0){ atomicAdd(&d[b*2], s); atomicAdd(&d[b*2+1], q); }
}

// ---------------------------------------------------------------------------
// Mega-prep 1 (inputs only): xhm weight pack [tap][Co][Ci] + stats zero +
// x/h/m fp32->bf16 transpose [b][1024px][64].
// Blocks 0..5599: weight pack.  Blocks 5600..6367: 48 plane-transposes x16.
// ---------------------------------------------------------------------------
__global__ __launch_bounds__(256) void k_pre(
    const float* __restrict__ wX, ushort* __restrict__ dX,
    const float* __restrict__ wH, ushort* __restrict__ dH,
    const float* __restrict__ wM, ushort* __restrict__ dM,
    const float* __restrict__ x_t, ushort* __restrict__ xT,
    const float* __restrict__ h_t, ushort* __restrict__ hT,
    const float* __restrict__ m_t, ushort* __restrict__ mT,
    float* __restrict__ zs)
{
  const int bid = blockIdx.x, t = threadIdx.x;
  __shared__ __align__(16) float T[64][68];
  if (bid < 5600){
    if (bid == 0) zs[t] = 0.f;
    int idx = bid*256 + t;
    const float* s; ushort* d; int Co;
    if (idx < 716800){ s=wX; d=dX; Co=448; }
    else if ((idx -= 716800) < 409600){ s=wH; d=dH; Co=256; }
    else if ((idx -= 409600) < 307200){ s=wM; d=dM; Co=192; }
    else return;
    int ci = idx & 63; int r = idx >> 6; int co = r % Co; int tap = r / Co;
    d[idx] = f2b(s[((size_t)(co*64 + ci))*25 + tap]);
    return;
  }
  const int j = bid - 5600;
  const int p0 = (j & 15) << 6;
  const int lp = j >> 4;                 // 0..47
  const float* src; ushort* outT; int pl;
  if (lp < 16){ src = x_t; outT = xT; pl = lp; }
  else if (lp < 32){ src = h_t; outT = hT; pl = lp - 16; }
  else { src = m_t; outT = mT; pl = lp - 32; }
  const float* sp = src + ((size_t)pl << 16);
  const int c = t >> 2, g = t & 3;
  #pragma unroll
  for (int i = 0; i < 4; ++i)
    *(float4*)&T[c][(g<<4)+(i<<2)] = *(const float4*)(sp + ((size_t)c << 10) + p0 + (g<<4) + (i<<2));
  __syncthreads();
  const int p = t >> 2, c0 = (t & 3) << 4;
  uint w4[8];
  #pragma unroll
  for (int k = 0; k < 8; ++k)
    w4[k] = (uint)f2b(T[c0+2*k][p]) | ((uint)f2b(T[c0+2*k+1][p]) << 16);
  ushort* dst = outT + ((((size_t)pl << 10) + p0 + p) << 6) + c0;
  *(uint4*)(dst)     = *(uint4*)&w4[0];
  *(uint4*)(dst + 8) = *(uint4*)&w4[4];
}

// ---------------------------------------------------------------------------
// Mega-prep 2 (after gates): o/sa/ca weight pack + chist->kvC/kvT +
// ft->ftC/qT + memo m-half -> memoT[b][px][128] (+64 offset).
// Blocks 0..1599: weights.  1600..3135: 96 plane jobs x16 p0-blocks.
// ---------------------------------------------------------------------------
__global__ __launch_bounds__(256) void k_postgates(
    const float* __restrict__ wO, ushort* __restrict__ dO,
    const float* __restrict__ wSA, ushort* __restrict__ dSA,
    const float* __restrict__ wCA, ushort* __restrict__ dCA,
    const float* __restrict__ chist, ushort* __restrict__ kvC, ushort* __restrict__ kvT,
    const float* __restrict__ ft, ushort* __restrict__ ftC, ushort* __restrict__ qT,
    const float* __restrict__ memo, ushort* __restrict__ memoT)
{
  const int bid = blockIdx.x, t = threadIdx.x;
  __shared__ __align__(16) float T[64][68];
  if (bid < 1600){
    int idx = bid*256 + t;
    const float* s; ushort* d; int Co, Ci;
    if (idx < 204800){ s=wO; d=dO; Co=64; Ci=128; }
    else if ((idx -= 204800) < 102400){ s=wSA; d=dSA; Co=64; Ci=64; }
    else if ((idx -= 102400) < 102400){ s=wCA; d=dCA; Co=64; Ci=64; }
    else return;
    int ci = idx % Ci; int r = idx / Ci; int co = r % Co; int tap = r / Co;
    d[idx] = f2b(s[((size_t)(co*Ci + ci))*25 + tap]);
    return;
  }
  const int j = bid - 1600;
  const int p0 = (j & 15) << 6;
  const int lp = j >> 4;                 // 0..95
  const int c = t >> 2, g = t & 3;
  if (lp < 80){
    const float* src; ushort* outC; ushort* outT; int pl;
    if (lp < 64){ src = chist; outC = kvC; outT = kvT; pl = lp; }
    else { src = ft; outC = ftC; outT = qT; pl = lp - 64; }
    const float* sp = src + ((size_t)pl << 16);
    #pragma unroll
    for (int i = 0; i < 4; ++i){
      float4 f = *(const float4*)(sp + ((size_t)c << 10) + p0 + (g<<4) + (i<<2));
      *(float4*)&T[c][(g<<4)+(i<<2)] = f;
      uint2 pk2;
      pk2.x = (uint)f2b(f.x) | ((uint)f2b(f.y) << 16);
      pk2.y = (uint)f2b(f.z) | ((uint)f2b(f.w) << 16);
      *(uint2*)(outC + ((((size_t)pl << 6) + c) << 10) + p0 + (g<<4) + (i<<2)) = pk2;
    }
    __syncthreads();
    const int p = t >> 2, c0 = (t & 3) << 4;
    uint w4[8];
    #pragma unroll
    for (int k = 0; k < 8; ++k)
      w4[k] = (uint)f2b(T[c0+2*k][p]) | ((uint)f2b(T[c0+2*k+1][p]) << 16);
    ushort* dst = outT + ((((size_t)pl << 10) + p0 + p) << 6) + c0;
    *(uint4*)(dst)     = *(uint4*)&w4[0];
    *(uint4*)(dst + 8) = *(uint4*)&w4[4];
  } else {
    const int b = lp - 80;               // memo m-half plane
    const float* sp = memo + ((size_t)(b*2 + 1) << 16);
    #pragma unroll
    for (int i = 0; i < 4; ++i)
      *(float4*)&T[c][(g<<4)+(i<<2)] = *(const float4*)(sp + ((size_t)c << 10) + p0 + (g<<4) + (i<<2));
    __syncthreads();
    const int p = t >> 2, c0 = (t & 3) << 4;
    uint w4[8];
    #pragma unroll
    for (int k = 0; k < 8; ++k)
      w4[k] = (uint)f2b(T[c0+2*k][p]) | ((uint)f2b(T[c0+2*k+1][p]) << 16);
    ushort* dst = memoT + ((((size_t)b << 10) + p0 + p) << 7) + 64 + c0;
    *(uint4*)(dst)     = *(uint4*)&w4[0];
    *(uint4*)(dst + 8) = *(uint4*)&w4[4];
  }
}

// ---------------------------------------------------------------------------
// Generic transpose prep with LayerNorm (for sp/ch after attention).
// ---------------------------------------------------------------------------
struct PT { const float* s; ushort* d; const float* st; const float* g; const float* bb; };

__global__ __launch_bounds__(256) void k_prepT3(PT ja, PT jb, PT jc, int n0, int n1, float invN)
{
  const int lp = blockIdx.y;
  PT j; int pl;
  if (lp < n0){ j = ja; pl = lp; }
  else if (lp < n0 + n1){ j = jb; pl = lp - n0; }
  else { j = jc; pl = lp - n0 - n1; }
  const float* sp = j.s + ((size_t)pl << 16);
  float mean = 0.f, rstd = 0.f;
  if (j.st){
    float s0 = j.st[pl*2], s1 = j.st[pl*2+1];
    mean = s0*invN; rstd = rsqrtf(s1*invN - mean*mean + 1e-5f);
  }
  const int p0 = blockIdx.x << 6;
  __shared__ __align__(16) float T[64][68];
  const int t = threadIdx.x, c = t >> 2, g4 = t & 3;
  #pragma unroll
  for (int i = 0; i < 4; ++i){
    const int px = (g4 << 4) + (i << 2);
    float4 f = *(const float4*)(sp + ((size_t)c << 10) + p0 + px);
    if (j.st){
      const size_t li = ((size_t)c << 10) + p0 + px;
      float4 gv = *(const float4*)(j.g + li);
      float4 bv = *(const float4*)(j.bb + li);
      f.x = (f.x - mean)*rstd*gv.x + bv.x;
      f.y = (f.y - mean)*rstd*gv.y + bv.y;
      f.z = (f.z - mean)*rstd*gv.z + bv.z;
      f.w = (f.w - mean)*rstd*gv.w + bv.w;
    }
    *(float4*)&T[c][px] = f;
  }
  __syncthreads();
  const int p = t >> 2, c0 = (t & 3) << 4;
  uint w4[8];
  #pragma unroll
  for (int k = 0; k < 8; ++k){
    ushort lo = f2b(T[c0 + 2*k][p]);
    ushort hi = f2b(T[c0 + 2*k + 1][p]);
    w4[k] = (uint)lo | ((uint)hi << 16);
  }
  ushort* dst = j.d + ((((size_t)pl << 10) + p0 + p) << 6) + c0;
  *(uint4*)(dst)     = *(uint4*)&w4[0];
  *(uint4*)(dst + 8) = *(uint4*)&w4[4];
}

// ---------------------------------------------------------------------------
// Fused multi-segment MFMA 5x5 SAME conv (round-2 verified schedule).
// ---------------------------------------------------------------------------
struct Seg {
  const ushort* inT; const ushort* w; const float* bias;
  float* out; float* ostat;
  int Cin, Cout;
};
struct Segs3 { Seg s[3]; int b1, b2; };

template<int MT, int RPB>
__global__ __launch_bounds__(256, MT==4 ? 2 : 3) void k_convX(Segs3 Sg)
{
  constexpr int CO   = MT*16;
  constexpr int NW   = 5*CO*4;                 // uint4 units per dy-group
  constexpr int ITW  = (NW + 255) / 256;
  constexpr int DXSH = (MT == 4 ? 8 : 7);      // u >> DXSH = dx
  constexpr int PXB  = 32/RPB;                 // pixel-blocks per image
  constexpr int ROWS = RPB + 4;
  constexpr int RPW  = RPB/4;                  // rows per wave
  constexpr int NTIL = RPB/2;                  // 16-px n-tiles per wave
  constexpr int SUN2 = ROWS*36;

  const int b = blockIdx.y;
  const int cog = blockIdx.x / PXB, pxblk = blockIdx.x % PXB;
  const int si = (cog >= Sg.b1) + (cog >= Sg.b2);
  const Seg sg = Sg.s[si];
  const int base = si == 0 ? 0 : (si == 1 ? Sg.b1 : Sg.b2);
  const int co0 = (cog - base) * CO;
  const int r0 = pxblk * RPB;
  const int t = threadIdx.x, w = t >> 6, l = t & 63;
  const int lane16 = l & 15, quad = l >> 4;

  __shared__ __align__(16) ushort S_[4][ROWS][36][8];  // input [ci-quad][row][col][8ci]
  __shared__ __align__(16) ushort W_[2][5*CO*32];      // [buf][u*8]

  f4v acc[MT][NTIL];
  #pragma unroll
  for (int mi = 0; mi < MT; ++mi)
    #pragma unroll
    for (int n = 0; n < NTIL; ++n) acc[mi][n] = (f4v){0.f,0.f,0.f,0.f};

  size_t woff0[ITW];
  #pragma unroll
  for (int it = 0; it < ITW; ++it){
    const int u = t + it*256;
    const int l16u = u & 15, qu = (u >> 4) & 3;
    const int miu = (u >> 6) & (MT - 1), dxu = u >> DXSH;
    woff0[it] = ((size_t)(dxu*sg.Cout + co0 + miu*16 + l16u))*sg.Cin + (qu << 3);
  }
  const size_t wdy = (size_t)5 * sg.Cout * sg.Cin;   // one dy-row of taps

  const int ncc = sg.Cin >> 5;
  for (int cc = 0; cc < ncc; ++cc){
    __syncthreads();
    // ---- stage input stripe ----
    for (int idx = t; idx < SUN2; idx += 256){
      const int row = idx / 36, col = idx - row*36;
      const int ir = r0 - 2 + row, ic = col - 2;
      uint4 pk[4] = {make_uint4(0,0,0,0),make_uint4(0,0,0,0),make_uint4(0,0,0,0),make_uint4(0,0,0,0)};
      if ((unsigned)ir < 32u && (unsigned)ic < 32u){
        const ushort* bp = sg.inT + ((size_t)((b << 10) + (ir << 5) + ic)) * sg.Cin + (cc << 5);
        #pragma unroll
        for (int q = 0; q < 4; ++q) pk[q] = *(const uint4*)(bp + (q << 3));
      }
      #pragma unroll
      for (int q = 0; q < 4; ++q) *(uint4*)&S_[q][row][col][0] = pk[q];
    }
    // ---- stage weight group dy=0 ----
    {
      uint4 wreg[ITW];
      #pragma unroll
      for (int it = 0; it < ITW; ++it)
        if (ITW*256 == NW || t + it*256 < NW)
          wreg[it] = *(const uint4*)(sg.w + woff0[it] + (cc << 5));
      #pragma unroll
      for (int it = 0; it < ITW; ++it)
        if (ITW*256 == NW || t + it*256 < NW)
          *(uint4*)&W_[0][(size_t)(t + it*256) * 8] = wreg[it];
    }
    __syncthreads();
    #pragma unroll
    for (int dy = 0; dy < 5; ++dy){
      uint4 nreg[ITW];
      if (dy < 4){
        #pragma unroll
        for (int it = 0; it < ITW; ++it)
          if (ITW*256 == NW || t + it*256 < NW)
            nreg[it] = *(const uint4*)(sg.w + woff0[it] + (size_t)(dy+1)*wdy + (cc << 5));
      }
      #pragma unroll
      for (int dx = 0; dx < 5; ++dx){
        s8v a[MT];
        #pragma unroll
        for (int mi = 0; mi < MT; ++mi){
          const int au = ((((dx*MT + mi) << 2) + quad) << 4) + lane16;
          a[mi] = *(const s8v*)&W_[dy & 1][au << 3];
        }
        #pragma unroll
        for (int n = 0; n < NTIL; ++n){
          const int srow = w*RPW + (n >> 1) + dy;
          const int col = ((n & 1) << 4) + lane16 + dx;
          s8v bb = *(const s8v*)&S_[quad][srow][col][0];
          #pragma unroll
          for (int mi = 0; mi < MT; ++mi)
            acc[mi][n] = __builtin_amdgcn_mfma_f32_16x16x32_bf16(a[mi], bb, acc[mi][n], 0, 0, 0);
        }
      }
      if (dy < 4){
        #pragma unroll
        for (int it = 0; it < ITW; ++it)
          if (ITW*256 == NW || t + it*256 < NW)
            *(uint4*)&W_[(dy+1) & 1][(size_t)(t + it*256) * 8] = nreg[it];
      }
      __syncthreads();
    }
  }
  // ---- epilogue ----
  float lsum = 0.f, lsq = 0.f;
  #pragma unroll
  for (int mi = 0; mi < MT; ++mi){
    const int co = co0 + mi*16 + (quad << 2);
    #pragma unroll
    for (int n = 0; n < NTIL; ++n){
      const int row = r0 + w*RPW + (n >> 1);
      const int col = ((n & 1) << 4) + lane16;
      #pragma unroll
      for (int i = 0; i < 4; ++i){
        float v = acc[mi][n][i] + (sg.bias ? sg.bias[co+i] : 0.f);
        sg.out[(((size_t)(b*sg.Cout + co + i)) << 10) + (row << 5) + col] = v;
        lsum += v; lsq += v*v;
      }
    }
  }
  if (sg.ostat) red_atomic2(lsum, lsq, sg.ostat, b, t);
}

// ---------------------------------------------------------------------------
// Gates
// ---------------------------------------------------------------------------
__global__ __launch_bounds__(256) void k_gates(
    const float* __restrict__ bufx, const float* __restrict__ bufh, const float* __restrict__ bufm,
    const float* __restrict__ lnxg, const float* __restrict__ lnxb,
    const float* __restrict__ lnhg, const float* __restrict__ lnhb,
    const float* __restrict__ lnmg, const float* __restrict__ lnmb,
    const float* __restrict__ m_t, const float* __restrict__ stats,
    float* __restrict__ ft, float* __restrict__ ig, float* __restrict__ osum,
    float* __restrict__ memo, float* __restrict__ out_m)
{
  const int idx = blockIdx.x*256 + threadIdx.x;
  const int b = idx >> 16, rem = idx & 65535;
  const int c = rem >> 10, p = rem & 1023;

  float mx = stats[b*2]      * (1.f/458752.f);
  float vx = stats[b*2+1]    * (1.f/458752.f) - mx*mx;  float rx = rsqrtf(vx + 1e-5f);
  float mh = stats[32+b*2]   * (1.f/262144.f);
  float vh = stats[32+b*2+1] * (1.f/262144.f) - mh*mh;  float rh = rsqrtf(vh + 1e-5f);
  float mm = stats[64+b*2]   * (1.f/196608.f);
  float vm = stats[64+b*2+1] * (1.f/196608.f) - mm*mm;  float rm = rsqrtf(vm + 1e-5f);

  auto LX = [&](int k){
    size_t ch = (size_t)k*64 + c; size_t gi = ((size_t)b*448 + ch)*1024 + p; size_t li = ch*1024 + p;
    return (bufx[gi] - mx)*rx*lnxg[li] + lnxb[li]; };
  auto LH = [&](int k){
    size_t ch = (size_t)k*64 + c; size_t gi = ((size_t)b*256 + ch)*1024 + p; size_t li = ch*1024 + p;
    return (bufh[gi] - mh)*rh*lnhg[li] + lnhb[li]; };
  auto LM = [&](int k){
    size_t ch = (size_t)k*64 + c; size_t gi = ((size_t)b*192 + ch)*1024 + p; size_t li = ch*1024 + p;
    return (bufm[gi] - mm)*rm*lnmg[li] + lnmb[li]; };

  float i_t = sigm(LX(0) + LH(0));
  float f_t = sigm(LX(1) + LH(1) + 1.f);
  float g_t = tanh_(LX(2) + LH(2));
  float i_p = sigm(LX(3) + LM(0));
  float f_p = sigm(LX(4) + LM(1) + 1.f);
  float g_p = tanh_(LX(5) + LM(2));
  float ox = LX(6), oh = LH(3);

  ft[idx]   = f_t;
  ig[idx]   = i_t * g_t;
  osum[idx] = ox + oh;
  float mn = f_p * m_t[idx] + i_p * g_p;
  out_m[idx] = mn;
  memo[((size_t)(b*128 + 64 + c) << 10) + p] = mn;
}

// ---------------------------------------------------------------------------
// Fused spatial attention (kv-split x2, additive num/den partials) and
// channel-attn logits.  Blocks 0..511: spat (p0,b,half).  512..639: chlog.
// LDS shared via char buffer (max = spat's 44288 B).
// ---------------------------------------------------------------------------
__global__ __launch_bounds__(256) void k_spat_chlog(
    const ushort* __restrict__ qT, const ushort* __restrict__ kvC, const ushort* __restrict__ kvT,
    float* __restrict__ num, float* __restrict__ den,
    const ushort* __restrict__ ftC, float* __restrict__ lg)
{
  __shared__ __align__(16) char smem[44288];
  const int bid = blockIdx.x, t = threadIdx.x;
  const int w = t >> 6, l = t & 63;
  const int lane16 = l & 15, quad = l >> 4;

  if (bid < 512){
    const int p0 = (bid & 15) << 6, b = (bid >> 4) & 15, half = bid >> 8;
    ushort (*Kt)[72] = reinterpret_cast<ushort(*)[72]>(smem);
    ushort (*Kc)[72] = reinterpret_cast<ushort(*)[72]>(smem + 9216);
    ushort (*Eb)[72] = reinterpret_cast<ushort(*)[72]>(smem + 18432);
    float  (*XO)[65] = reinterpret_cast<float(*)[65]>(smem + 27648);

    s8v qa0, qa1;
    {
      const ushort* qr = qT + ((((size_t)b << 10) + p0 + (w << 4) + lane16) << 6) + (quad << 3);
      qa0 = *(const s8v*)(qr);
      qa1 = *(const s8v*)(qr + 32);
    }
    f4v o0 = {0.f,0.f,0.f,0.f}, o1 = o0, o2 = o0, o3 = o0, dacc = o0;
    const short oneb = (short)0x3F80;
    const s8v ones = { oneb, oneb, oneb, oneb, oneb, oneb, oneb, oneb };

    const int r = t >> 2, g4 = (t & 3) << 4;
    for (int ck = 0; ck < 32; ++ck){
      const int chunk = (half << 5) + ck;
      const int lidx = chunk >> 4, pk = (chunk & 15) << 6;
      __syncthreads();
      {
        const ushort* sc = kvC + ((((size_t)(b*4 + lidx) << 6) + r) << 10) + pk + g4;
        *(uint4*)&Kc[r][g4]     = *(const uint4*)(sc);
        *(uint4*)&Kc[r][g4 + 8] = *(const uint4*)(sc + 8);
        const ushort* st = kvT + ((((size_t)(b*4 + lidx) << 10) + pk + r) << 6) + g4;
        *(uint4*)&Kt[r][g4]     = *(const uint4*)(st);
        *(uint4*)&Kt[r][g4 + 8] = *(const uint4*)(st + 8);
      }
      __syncthreads();
      #pragma unroll
      for (int nt = 0; nt < 4; ++nt){
        const ushort* bt = &Kt[(nt << 4) + lane16][quad << 3];
        s8v b0 = *(const s8v*)(bt);
        s8v b1 = *(const s8v*)(bt + 32);
        f4v s = {0.f,0.f,0.f,0.f};
        s = __builtin_amdgcn_mfma_f32_16x16x32_bf16(qa0, b0, s, 0, 0, 0);
        s = __builtin_amdgcn_mfma_f32_16x16x32_bf16(qa1, b1, s, 0, 0, 0);
        #pragma unroll
        for (int i = 0; i < 4; ++i){
          float e = __expf(s[i] - 12.f);
          Eb[(w << 4) + (quad << 2) + i][(nt << 4) + lane16] = f2b(e);
        }
      }
      __syncthreads();
      #pragma unroll
      for (int ks = 0; ks < 2; ++ks){
        s8v ea = *(const s8v*)&Eb[(w << 4) + lane16][(ks << 5) + (quad << 3)];
        dacc = __builtin_amdgcn_mfma_f32_16x16x32_bf16(ea, ones, dacc, 0, 0, 0);
        s8v bc0 = *(const s8v*)&Kc[ 0 + lane16][(ks << 5) + (quad << 3)];
        s8v bc1 = *(const s8v*)&Kc[16 + lane16][(ks << 5) + (quad << 3)];
        s8v bc2 = *(const s8v*)&Kc[32 + lane16][(ks << 5) + (quad << 3)];
        s8v bc3 = *(const s8v*)&Kc[48 + lane16][(ks << 5) + (quad << 3)];
        o0 = __builtin_amdgcn_mfma_f32_16x16x32_bf16(ea, bc0, o0, 0, 0, 0);
        o1 = __builtin_amdgcn_mfma_f32_16x16x32_bf16(ea, bc1, o1, 0, 0, 0);
        o2 = __builtin_amdgcn_mfma_f32_16x16x32_bf16(ea, bc2, o2, 0, 0, 0);
        o3 = __builtin_amdgcn_mfma_f32_16x16x32_bf16(ea, bc3, o3, 0, 0, 0);
      }
    }
    {
      const int pxl = (w << 4) + (quad << 2);
      if (lane16 == 0){
        float* dp = den + (((size_t)(half*16 + b)) << 10) + p0 + pxl;
        dp[0] = dacc[0]; dp[1] = dacc[1]; dp[2] = dacc[2]; dp[3] = dacc[3];
      }
      XO[ 0 + lane16][pxl+0] = o0[0]; XO[ 0 + lane16][pxl+1] = o0[1];
      XO[ 0 + lane16][pxl+2] = o0[2]; XO[ 0 + lane16][pxl+3] = o0[3];
      XO[16 + lane16][pxl+0] = o1[0]; XO[16 + lane16][pxl+1] = o1[1];
      XO[16 + lane16][pxl+2] = o1[2]; XO[16 + lane16][pxl+3] = o1[3];
      XO[32 + lane16][pxl+0] = o2[0]; XO[32 + lane16][pxl+1] = o2[1];
      XO[32 + lane16][pxl+2] = o2[2]; XO[32 + lane16][pxl+3] = o2[3];
      XO[48 + lane16][pxl+0] = o3[0]; XO[48 + lane16][pxl+1] = o3[1];
      XO[48 + lane16][pxl+2] = o3[2]; XO[48 + lane16][pxl+3] = o3[3];
    }
    __syncthreads();
    {
      const int ch = t >> 2;
      float* nout = num + (size_t)half * N1;
      #pragma unroll
      for (int i = 0; i < 4; ++i){
        size_t gi = ((size_t)b << 16) + ((size_t)ch << 10) + p0 + g4 + (i << 2);
        float4 ov;
        ov.x = XO[ch][g4 + (i << 2) + 0];
        ov.y = XO[ch][g4 + (i << 2) + 1];
        ov.z = XO[ch][g4 + (i << 2) + 2];
        ov.w = XO[ch][g4 + (i << 2) + 3];
        *(float4*)(nout + gi) = ov;
      }
    }
  } else {
    const int j = bid - 512;
    const int bx = j & 7, b = j >> 3;
    const int np = bx >> 1, mp = bx & 1;
    ushort (*As)[32][8] = reinterpret_cast<ushort(*)[32][8]>(smem);
    ushort (*Bs)[64][8] = reinterpret_cast<ushort(*)[64][8]>(smem + 4096);
    f4v acc[2];
    acc[0] = (f4v){0.f,0.f,0.f,0.f}; acc[1] = (f4v){0.f,0.f,0.f,0.f};

    for (int kc = 0; kc < 16; ++kc){
      __syncthreads();
      {
        const int c = t >> 3, q = t & 7;
        *(uint4*)&As[q][c][0] = *(const uint4*)(ftC + (((size_t)(b*64 + mp*32 + c)) << 10) + (kc<<6) + (q<<3));
      }
      #pragma unroll
      for (int it = 0; it < 2; ++it){
        const int idx = t + it*256;
        const int r2 = idx >> 3, q = idx & 7;
        *(uint4*)&Bs[q][r2][0] = *(const uint4*)(kvC + ((((size_t)(b*4 + np) << 6) + r2) << 10) + (kc<<6) + (q<<3));
      }
      __syncthreads();
      #pragma unroll
      for (int ks = 0; ks < 2; ++ks){
        s8v a0 = *(const s8v*)&As[(ks<<2)+quad][lane16][0];
        s8v a1 = *(const s8v*)&As[(ks<<2)+quad][16 + lane16][0];
        s8v bb = *(const s8v*)&Bs[(ks<<2)+quad][(w<<4) + lane16][0];
        acc[0] = __builtin_amdgcn_mfma_f32_16x16x32_bf16(a0, bb, acc[0], 0, 0, 0);
        acc[1] = __builtin_amdgcn_mfma_f32_16x16x32_bf16(a1, bb, acc[1], 0, 0, 0);
      }
    }
    #pragma unroll
    for (int mi = 0; mi < 2; ++mi)
      #pragma unroll
      for (int i = 0; i < 4; ++i){
        const int c = mp*32 + mi*16 + (quad<<2) + i;
        const int n = (np<<6) + (w<<4) + lane16;
        lg[(((size_t)(b*64 + c)) << 8) + n] = acc[mi][i];
      }
  }
}

// ---------------------------------------------------------------------------
// Fused channel-softmax (blocks 0..255) and spatial combine (256..511).
// ---------------------------------------------------------------------------
__global__ __launch_bounds__(256) void k_chsm_spcomb(
    const float* __restrict__ a, ushort* __restrict__ ab,
    const float* __restrict__ num, const float* __restrict__ den,
    const float* __restrict__ c_t, float* __restrict__ sp_raw, float* __restrict__ stats)
{
  const int bid = blockIdx.x, t = threadIdx.x;
  if (bid < 256){
    const int row  = bid*4 + (t >> 6);
    const int lane = t & 63;
    const float* rp = a + ((size_t)row << 8);
    float v0 = rp[lane], v1 = rp[lane+64], v2 = rp[lane+128], v3 = rp[lane+192];
    float mx = fmaxf(fmaxf(v0, v1), fmaxf(v2, v3));
    #pragma unroll
    for (int m = 32; m; m >>= 1) mx = fmaxf(mx, __shfl_xor(mx, m));
    v0 = __expf(v0 - mx); v1 = __expf(v1 - mx); v2 = __expf(v2 - mx); v3 = __expf(v3 - mx);
    float s = v0 + v1 + v2 + v3;
    #pragma unroll
    for (int m = 32; m; m >>= 1) s += __shfl_xor(s, m);
    float inv = 1.f / s;
    ushort* op = ab + ((size_t)row << 8);
    op[lane] = f2b(v0*inv); op[lane+64] = f2b(v1*inv);
    op[lane+128] = f2b(v2*inv); op[lane+192] = f2b(v3*inv);
  } else {
    const int j = bid - 256;
    const int p0 = (j & 15) << 6, b = j >> 4;
    const int ch = t >> 2, g4 = (t & 3) << 4;
    float lsum = 0.f, lsq = 0.f;
    #pragma unroll
    for (int i = 0; i < 4; ++i){
      const int px = p0 + g4 + (i << 2);
      size_t gi = ((size_t)b << 16) + ((size_t)ch << 10) + px;
      float4 n0 = *(const float4*)(num + gi);
      float4 n1 = *(const float4*)(num + (size_t)N1 + gi);
      const float* d0 = den + (((size_t)b) << 10) + px;
      const float* d1 = den + (((size_t)(16 + b)) << 10) + px;
      float4 cv = *(const float4*)(c_t + gi);
      float4 ov;
      ov.x = cv.x + (n0.x + n1.x) / (d0[0] + d1[0]);
      ov.y = cv.y + (n0.y + n1.y) / (d0[1] + d1[1]);
      ov.z = cv.z + (n0.z + n1.z) / (d0[2] + d1[2]);
      ov.w = cv.w + (n0.w + n1.w) / (d0[3] + d1[3]);
      *(float4*)(sp_raw + gi) = ov;
      lsum += ov.x + ov.y + ov.z + ov.w;
      lsq  += ov.x*ov.x + ov.y*ov.y + ov.z*ov.z + ov.w*ov.w;
    }
    red_atomic2(lsum, lsq, stats, b, t);
  }
}

// ---------------------------------------------------------------------------
// Channel attention output via MFMA.  Grid (16,16): 64-px chunks.
// ---------------------------------------------------------------------------
__global__ __launch_bounds__(256) void k_chout_m(
    const ushort* __restrict__ chlb, const ushort* __restrict__ kvT,
    const float* __restrict__ c_t, float* __restrict__ ch_raw, float* __restrict__ stats)
{
  const int p0 = blockIdx.x << 6, b = blockIdx.y;
  const int t = threadIdx.x, w = t >> 6, l = t & 63;
  const int lane16 = l & 15, quad = l >> 4;
  __shared__ __align__(16) ushort As[32][64][8];
  __shared__ __align__(16) ushort Bs[32][32][8];
  #pragma unroll
  for (int it = 0; it < 8; ++it){
    const int idx = t + it*256;
    const int c = idx >> 5, q = idx & 31;
    *(uint4*)&As[q][c][0] = *(const uint4*)(chlb + (((size_t)(b*64 + c)) << 8) + (q<<3));
  }
  __syncthreads();
  s8v a[8];
  #pragma unroll
  for (int ks = 0; ks < 8; ++ks)
    a[ks] = *(const s8v*)&As[(ks<<2)+quad][(w<<4) + lane16][0];
  float lsum = 0.f, lsq = 0.f;
  for (int pc = 0; pc < 2; ++pc){
    __syncthreads();
    #pragma unroll
    for (int it = 0; it < 4; ++it){
      const int idx = t + it*256;
      const int px = idx >> 5, q = idx & 31;
      const int plane = (b<<2) + (q>>3);
      *(uint4*)&Bs[q][px][0] = *(const uint4*)(kvT + ((((size_t)plane << 10) + p0 + (pc<<5) + px) << 6) + ((q&7)<<3));
    }
    __syncthreads();
    #pragma unroll
    for (int nt = 0; nt < 2; ++nt){
      f4v o = {0.f,0.f,0.f,0.f};
      #pragma unroll
      for (int ks = 0; ks < 8; ++ks){
        s8v bb = *(const s8v*)&Bs[(ks<<2)+quad][(nt<<4) + lane16][0];
        o = __builtin_amdgcn_mfma_f32_16x16x32_bf16(a[ks], bb, o, 0, 0, 0);
      }
      #pragma unroll
      for (int i = 0; i < 4; ++i){
        const int c = (w<<4) + (quad<<2) + i;
        const int px = p0 + (pc<<5) + (nt<<4) + lane16;
        size_t gi = ((size_t)b << 16) + ((size_t)c << 10) + px;
        float v = c_t[gi] + o[i];
        ch_raw[gi] = v;
        lsum += v; lsq += v*v;
      }
    }
  }
  red_atomic2(lsum, lsq, stats, b, t);
}

// ---------------------------------------------------------------------------
// LN+relu both attention branches, 1x1 convs, sum, 1x1 attn_w, c_new.
// Also writes the bf16-transposed c-half of memoT (replaces prepTm).
// ---------------------------------------------------------------------------
__global__ __launch_bounds__(256) void k_attnfinal(
    const float* __restrict__ samid, const float* __restrict__ camid,
    const float* __restrict__ stats_sa, const float* __restrict__ stats_ca,
    const float* __restrict__ salng, const float* __restrict__ salnb,
    const float* __restrict__ calng, const float* __restrict__ calnb,
    const float* __restrict__ wsa2, const float* __restrict__ wca2,
    const float* __restrict__ cab2, const float* __restrict__ wat,
    const float* __restrict__ ig, float* __restrict__ out_c, float* __restrict__ memo,
    ushort* __restrict__ memoT)
{
  const int p0 = blockIdx.x << 6, b = blockIdx.y, t = threadIdx.x;
  const int tc = t & 15, tp = t >> 4;
  __shared__ __align__(16) float R[64][68];
  __shared__ __align__(16) float Wl[64][68];
  __shared__ __align__(16) float Ms[64][68];
  const float invN = 1.f/65536.f;
  float acc[4][4] = {};
  #pragma unroll
  for (int pass = 0; pass < 2; ++pass){
    const float* mid = pass ? camid : samid;
    const float* st  = pass ? stats_ca : stats_sa;
    const float* g   = pass ? calng : salng;
    const float* bb  = pass ? calnb : salnb;
    const float* w   = pass ? wca2  : wsa2;
    float mean = st[b*2]*invN;
    float var  = st[b*2+1]*invN - mean*mean;
    float rstd = rsqrtf(var + 1e-5f);
    __syncthreads();
    {
      const int j = t & 63, c0 = t >> 6;
      for (int ci = c0; ci < 64; ci += 4){
        size_t gi = ((size_t)b << 16) + ((size_t)ci << 10) + p0 + j;
        size_t li = ((size_t)ci << 10) + p0 + j;
        float v = (mid[gi] - mean)*rstd*g[li] + bb[li];
        R[ci][j] = fmaxf(v, 0.f);
      }
      const int ci2 = t & 63, c20 = t >> 6;
      for (int c2 = c20; c2 < 64; c2 += 4) Wl[ci2][c2] = w[((size_t)c2 << 6) + ci2];
    }
    __syncthreads();
    for (int ci = 0; ci < 64; ++ci){
      float wv[4], rv[4];
      *(float4*)wv = *(const float4*)&Wl[ci][4*tc];
      *(float4*)rv = *(const float4*)&R[ci][4*tp];
      #pragma unroll
      for (int i = 0; i < 4; ++i)
        #pragma unroll
        for (int j = 0; j < 4; ++j)
          acc[i][j] = fmaf(wv[i], rv[j], acc[i][j]);
    }
  }
  {
    float b2[4];
    #pragma unroll
    for (int i = 0; i < 4; ++i) b2[i] = cab2[4*tc + i];
    #pragma unroll
    for (int i = 0; i < 4; ++i)
      #pragma unroll
      for (int j = 0; j < 4; ++j)
        Ms[4*tc+i][4*tp+j] = acc[i][j] + b2[i];
  }
  __syncthreads();
  {
    const int ci2 = t & 63, c20 = t >> 6;
    for (int c2 = c20; c2 < 64; c2 += 4) Wl[ci2][c2] = wat[((size_t)c2 << 6) + ci2];
  }
  __syncthreads();
  float acc2[4][4] = {};
  for (int c2 = 0; c2 < 64; ++c2){
    float wv[4], mv[4];
    *(float4*)wv = *(const float4*)&Wl[c2][4*tc];
    *(float4*)mv = *(const float4*)&Ms[c2][4*tp];
    #pragma unroll
    for (int i = 0; i < 4; ++i)
      #pragma unroll
      for (int j = 0; j < 4; ++j)
        acc2[i][j] = fmaf(wv[i], mv[j], acc2[i][j]);
  }
  float vv[4][4];
  #pragma unroll
  for (int i = 0; i < 4; ++i)
    #pragma unroll
    for (int j = 0; j < 4; ++j){
      size_t gi = ((size_t)b << 16) + ((size_t)(4*tc + i) << 10) + p0 + 4*tp + j;
      float v = acc2[i][j] + ig[gi];
      vv[i][j] = v;
      out_c[gi] = v;
      memo[((size_t)(b*128 + 4*tc + i) << 10) + p0 + 4*tp + j] = v;
    }
  #pragma unroll
  for (int j = 0; j < 4; ++j){
    uint2 pk;
    pk.x = (uint)f2b(vv[0][j]) | ((uint)f2b(vv[1][j]) << 16);
    pk.y = (uint)f2b(vv[2][j]) | ((uint)f2b(vv[3][j]) << 16);
    *(uint2*)(memoT + ((((size_t)b << 10) + p0 + 4*tp + j) << 7) + 4*tc) = pk;
  }
}

// ---------------------------------------------------------------------------
__global__ __launch_bounds__(256) void k_final(
    const float* __restrict__ memo, const float* __restrict__ wlast,
    const float* __restrict__ bufo, const float* __restrict__ osum,
    const float* __restrict__ stats_o, const float* __restrict__ lnog, const float* __restrict__ lnob,
    float* __restrict__ out_h)
{
  const int p0 = blockIdx.x << 6, b = blockIdx.y, t = threadIdx.x;
  const int tc = t & 15, tp = t >> 4;
  __shared__ __align__(16) float Msh[64][68];
  __shared__ __align__(16) float Wt[64][68];
  float acc[4][4] = {};
  #pragma unroll
  for (int half = 0; half < 2; ++half){
    __syncthreads();
    {
      const int j = t & 63, c0 = t >> 6;
      for (int ci = c0; ci < 64; ci += 4)
        Msh[ci][j] = memo[((size_t)(b*128 + half*64 + ci) << 10) + p0 + j];
      const int ci2 = t & 63, co0 = t >> 6;
      for (int co = co0; co < 64; co += 4) Wt[ci2][co] = wlast[((size_t)co << 7) + half*64 + ci2];
    }
    __syncthreads();
    for (int ci = 0; ci < 64; ++ci){
      float wv[4], mv[4];
      *(float4*)wv = *(const float4*)&Wt[ci][4*tc];
      *(float4*)mv = *(const float4*)&Msh[ci][4*tp];
      #pragma unroll
      for (int i = 0; i < 4; ++i)
        #pragma unroll
        for (int j = 0; j < 4; ++j)
          acc[i][j] = fmaf(wv[i], mv[j], acc[i][j]);
    }
  }
  float mean = stats_o[b*2]*(1.f/65536.f);
  float var  = stats_o[b*2+1]*(1.f/65536.f) - mean*mean;
  float rstd = rsqrtf(var + 1e-5f);
  #pragma unroll
  for (int i = 0; i < 4; ++i)
    #pragma unroll
    for (int j = 0; j < 4; ++j){
      const int co = 4*tc + i, p = p0 + 4*tp + j;
      size_t gi = ((size_t)b << 16) + ((size_t)co << 10) + p;
      size_t li = ((size_t)co << 10) + p;
      float lno = (bufo[gi] - mean)*rstd*lnog[li] + lnob[li];
      float o = sigm(osum[gi] + lno);
      out_h[gi] = o * tanh_(acc[i][j]);
    }
}

// ---------------------------------------------------------------------------
extern "C" void kernel_launch(void* const* d_in, const int* in_sizes, int n_in,
                              void* d_out, int out_size, void* d_ws, size_t ws_size,
                              hipStream_t stream)
{
  const float* x_t   = (const float*)d_in[0];
  const float* h_t   = (const float*)d_in[1];
  const float* c_t   = (const float*)d_in[2];
  const float* chist = (const float*)d_in[3];
  const float* m_t   = (const float*)d_in[4];
  const float* w_x   = (const float*)d_in[5];
  const float* lnxg  = (const float*)d_in[6];
  const float* lnxb  = (const float*)d_in[7];
  const float* w_h   = (const float*)d_in[8];
  const float* lnhg  = (const float*)d_in[9];
  const float* lnhb  = (const float*)d_in[10];
  const float* w_m   = (const float*)d_in[11];
  const float* lnmg  = (const float*)d_in[12];
  const float* lnmb  = (const float*)d_in[13];
  const float* w_o   = (const float*)d_in[14];
  const float* lnog  = (const float*)d_in[15];
  const float* lnob  = (const float*)d_in[16];
  const float* w_last= (const float*)d_in[17];
  const float* sng   = (const float*)d_in[18];
  const float* snb   = (const float*)d_in[19];
  const float* cng   = (const float*)d_in[20];
  const float* cnb   = (const float*)d_in[21];
  const float* ca_w1 = (const float*)d_in[22];
  const float* ca_b1 = (const float*)d_in[23];
  const float* calng = (const float*)d_in[24];
  const float* calnb = (const float*)d_in[25];
  const float* ca_w2 = (const float*)d_in[26];
  const float* ca_b2 = (const float*)d_in[27];
  const float* sa_w1 = (const float*)d_in[28];
  const float* salng = (const float*)d_in[29];
  const float* salnb = (const float*)d_in[30];
  const float* sa_w2 = (const float*)d_in[31];
  const float* attn_w= (const float*)d_in[32];

  float* out = (float*)d_out;
  float* ws  = (float*)d_ws;

  float* stats = ws;                        // 8 groups x 16 batches x {sum,sumsq}
  float* bufx  = ws + 1024;                 // 7*N1 raw conv_x
  float* bufh  = bufx + 7*(size_t)N1;       // 4*N1
  float* bufm  = bufh + 4*(size_t)N1;       // 3*N1
  float* ft    = bufm + 3*(size_t)N1;       // N1
  float* ig    = ft   + (size_t)N1;         // N1
  float* osum  = ig   + (size_t)N1;         // N1
  float* memo  = osum + (size_t)N1;         // 2*N1
  // aliases valid AFTER k_gates consumed bufx/h/m:
  float* sp    = bufx;                      // N1 (spat num0, then sp in-place)
  float* ch    = bufx + (size_t)N1;         // N1 (spat num1 until spcomb, then ch)
  float* samid = bufx + 2*(size_t)N1;       // N1
  float* camid = bufx + 3*(size_t)N1;       // N1
  float* bufo  = bufx + 4*(size_t)N1;       // N1
  float* chl   = bufx + 5*(size_t)N1;       // channel-attn logits fp32 (1 MB)
  ushort* kvC  = (ushort*)bufh;             // 4M bf16 (8 MB)
  ushort* kvT  = kvC + 4*(size_t)N1;        // 4M bf16 (8 MB)
  ushort* qT   = (ushort*)bufm;             // N1 ushorts
  ushort* ftC  = qT + (size_t)N1;           // N1 ushorts

  // transposed bf16 conv inputs:
  ushort* xT   = (ushort*)memo;             // N1 ushorts (dead before k_gates)
  ushort* hT   = xT + (size_t)N1;
  ushort* mT   = hT + (size_t)N1;
  ushort* spT  = ftC + (size_t)N1;          // N1 ushorts
  ushort* chT  = spT + (size_t)N1;          // N1 ushorts
  ushort* memoT = chT + (size_t)N1;         // 2*N1 ushorts (bufm tail, exact fit)
  float*  numB = bufx;                      // spat partial numerators [2][N1] (sp/ch slots)

  // bf16 weights: xhm pack lives in ft region (free until k_gates writes it)
  ushort* wbx = (ushort*)ft;                // 716800
  ushort* wbh = wbx + 716800;               // 409600
  ushort* wbm = wbh + 409600;               // 307200
  // o/sa/ca pack + bf16 probs + spat den live after chl in bufx region
  ushort* wbo  = (ushort*)(chl + 262144);   // 204800
  ushort* wbsa = wbo + 204800;              // 102400
  ushort* wbca = wbsa + 102400;             // 102400
  ushort* chlb = wbca + 102400;             // 262144 (bf16 probs)
  float*  denP = chl + 600000;              // [2][16][1024] spat denominators

  float* out_h = out;
  float* out_c = out + (size_t)N1;
  float* out_m = out + 2*(size_t)N1;

  // 1) input-only prep: xhm weights + stats zero + x/h/m transpose
  k_pre<<<dim3(6368), dim3(256), 0, stream>>>(w_x, wbx, w_h, wbh, w_m, wbm,
                                              x_t, xT, h_t, hT, m_t, mT, stats);

  // 2) fused x+h+m MFMA conv (stats: x=0, h=32, m=64)
  {
    Segs3 XHM;
    XHM.s[0] = Seg{ xT, wbx, nullptr, bufx, stats+0,  64, 448 };
    XHM.s[1] = Seg{ hT, wbh, nullptr, bufh, stats+32, 64, 256 };
    XHM.s[2] = Seg{ mT, wbm, nullptr, bufm, stats+64, 64, 192 };
    XHM.b1 = 7; XHM.b2 = 11;
    k_convX<4,8><<<dim3(56,16), dim3(256), 0, stream>>>(XHM);
  }

  // 3) gates
  k_gates<<<dim3(4096), dim3(256), 0, stream>>>(bufx, bufh, bufm, lnxg, lnxb, lnhg, lnhb,
                                                lnmg, lnmb, m_t, stats,
                                                ft, ig, osum, memo, out_m);

  // 4) fused post-gates prep: o/sa/ca weights + chist/ft prep + memoT m-half
  k_postgates<<<dim3(3136), dim3(256), 0, stream>>>(w_o, wbo, sa_w1, wbsa, ca_w1, wbca,
                                                    chist, kvC, kvT, ft, ftC, qT,
                                                    memo, memoT);

  // 5) spatial attention (z2 partials) || channel logits
  k_spat_chlog<<<dim3(640), dim3(256), 0, stream>>>(qT, kvC, kvT, numB, denP, ftC, chl);

  // 6) channel softmax || spatial combine (stats: sp=96)
  k_chsm_spcomb<<<dim3(512), dim3(256), 0, stream>>>(chl, chlb, numB, denP, c_t, sp, stats+96);

  // 7) channel attention output (stats: ch=128)
  k_chout_m<<<dim3(16,16), dim3(256), 0, stream>>>(chlb, kvT, c_t, ch, stats+128);

  // 8) LN + transpose sp/ch -> bf16
  {
    PT js{ sp, spT, stats+96,  sng, snb };
    PT jc{ ch, chT, stats+128, cng, cnb };
    k_prepT3<<<dim3(16,32), dim3(256), 0, stream>>>(js, jc, js, 16, 16, 1.f/65536.f);
  }

  // 9) fused sa+ca 5x5 MFMA convs (stats: sa=160, ca=192)
  {
    Segs3 SC;
    SC.s[0] = Seg{ spT, wbsa, nullptr, samid, stats+160, 64, 64 };
    SC.s[1] = Seg{ chT, wbca, ca_b1,   camid, stats+192, 64, 64 };
    SC.s[2] = SC.s[1];
    SC.b1 = 2; SC.b2 = 1000;
    k_convX<2,8><<<dim3(16,16), dim3(256), 0, stream>>>(SC);
  }

  // 10) attn final (also writes memoT c-half)
  k_attnfinal<<<dim3(16,16), dim3(256), 0, stream>>>(samid, camid, stats+160, stats+192,
                                                     salng, salnb, calng, calnb,
                                                     sa_w2, ca_w2, ca_b2, attn_w,
                                                     ig, out_c, memo, memoT);

  // 11) conv_o over mem (Cin=128) (stats: o=224)
  {
    Segs3 O;
    O.s[0] = Seg{ memoT, wbo, nullptr, bufo, stats+224, 128, 64 };
    O.s[1] = O.s[0]; O.s[2] = O.s[0];
    O.b1 = 1000; O.b2 = 1000;
    k_convX<2,8><<<dim3(8,16), dim3(256), 0, stream>>>(O);
  }

  // 12) final
  k_final<<<dim3(16,16), dim3(256), 0, stream>>>(memo, w_last, bufo, osum, stats+224,
                                                 lnog, lnob, out_h);
}